// Round 8
// baseline (2034.739 us; speedup 1.0000x reference)
//
#include <hip/hip_runtime.h>
#include <hip/hip_bf16.h>
#include <stdint.h>

#define B_ 8
#define T_ 10
#define N_ 50
#define IN_ 6
#define H_ 256
#define K_ 4
#define E_ 2450
#define ROWS 400           // B_*N_
#define AP 102400          // ROWS*H_
#define NBLK 256           // persistent grid: 1 block/CU guaranteed co-resident

typedef __attribute__((ext_vector_type(8))) __bf16 bf16x8;
typedef __attribute__((ext_vector_type(4))) float f32x4;

__device__ __forceinline__ unsigned short f2bf(float x) {
    unsigned int u = __float_as_uint(x);
    u = (u + 0x7fffu + ((u >> 16) & 1u)) >> 16;   // RNE
    return (unsigned short)u;
}
__device__ __forceinline__ unsigned pk2(float a, float b) {
    return (unsigned)f2bf(a) | ((unsigned)f2bf(b) << 16);
}
__device__ __forceinline__ float rcp_fast(float x) { return __builtin_amdgcn_rcpf(x); }
__device__ __forceinline__ float tanh_fast(float x) {
    float e = __expf(2.0f * x);
    return 1.0f - 2.0f * rcp_fast(e + 1.0f);
}
__device__ __forceinline__ float sigmoid_fast(float x) {
    return rcp_fast(1.0f + __expf(-x));
}

// ---------------- setup: weight swizzle + zero (hidden | hidden_bf | barrier) ----
__global__ __launch_bounds__(256) void swizzle_weights(
        const float* __restrict__ w1, const float* __restrict__ w2,
        const float* __restrict__ whr, const float* __restrict__ whi,
        const float* __restrict__ whh, const float* __restrict__ wo1,
        const float* __restrict__ wo2,
        unsigned short* __restrict__ w1s, unsigned short* __restrict__ w2s,
        unsigned short* __restrict__ gws, unsigned short* __restrict__ wos,
        unsigned int* __restrict__ zero_region) {
    const int W1N = 3 * 16 * 16 * 64 * 8;   // 393216
    const int W2N = 3 * 16 * 8 * 64 * 8;    // 196608
    const int GWN = 3 * 65536;              // 196608
    const int WON = 2 * 65536;              // 131072
    int idx = blockIdx.x * 256 + threadIdx.x;
    if (idx < W1N) {
        int j = idx & 7, L = (idx >> 3) & 63, kt = (idx >> 9) & 15;
        int nt = (idx >> 13) & 15, i = idx >> 17;
        int n = nt * 16 + (L & 15);
        int k = kt * 32 + ((L >> 4) << 3) + j;
        w1s[idx] = f2bf(w1[((size_t)(i + 1) * H_ + n) * (2 * H_) + k]);
    } else if (idx < W1N + W2N) {
        int t = idx - W1N;
        int j = t & 7, L = (t >> 3) & 63, kt = (t >> 9) & 7;
        int nt = (t >> 12) & 15, i = t >> 16;
        int n = nt * 16 + (L & 15);
        int k = kt * 32 + ((L >> 4) << 3) + j;
        w2s[t] = f2bf(w2[((size_t)(i + 1) * H_ + n) * H_ + k]);
    } else if (idx < W1N + W2N + GWN) {
        int t = idx - (W1N + W2N);
        int j = t & 7, L = (t >> 3) & 63, kt = (t >> 9) & 7;
        int nt = (t >> 12) & 15, mat = t >> 16;
        int n = nt * 16 + (L & 15);
        int k = kt * 32 + ((L >> 4) << 3) + j;
        const float* src = (mat == 0) ? whr : (mat == 1) ? whi : whh;
        gws[t] = f2bf(src[(size_t)n * H_ + k]);
    } else if (idx < W1N + W2N + GWN + WON) {
        int t = idx - (W1N + W2N + GWN);
        int j = t & 7, L = (t >> 3) & 63, kt = (t >> 9) & 7;
        int nt = (t >> 12) & 15, g = t >> 16;
        int n = nt * 16 + (L & 15);
        int k = kt * 32 + ((L >> 4) << 3) + j;
        const float* src = (g == 0) ? wo1 : wo2;
        wos[t] = f2bf(src[(size_t)n * H_ + k]);
    } else {
        int t = idx - (W1N + W2N + GWN + WON);
        if (t < 153664) zero_region[t] = 0u;   // hidden + hidden_bf + barrier
    }
}

// ---------------- grid barrier (monotone counter; all 256 blocks co-resident) ----
__device__ __forceinline__ void gridbar(unsigned* cnt, unsigned lg) {
    __syncthreads();
    if (threadIdx.x == 0) {
        __threadfence();                       // release
        atomicAdd(cnt, 1u);
        unsigned target = (unsigned)NBLK * (lg + 1u);
        while (atomicAdd(cnt, 0u) < target) __builtin_amdgcn_s_sleep(2);
        __threadfence();                       // acquire
    }
    __syncthreads();
}

// ---------------- phase bodies ---------------------------------------------------
__device__ __forceinline__ void uv_body(
        int unit, const unsigned short* __restrict__ hb,
        const unsigned short* __restrict__ w1s, const float* __restrict__ b1,
        float* __restrict__ UV) {
    int mm = unit / 6;
    int tyh = unit % 6;
    int ty = tyh >> 1, half = tyh & 1;
    int lane = threadIdx.x & 63, wid = threadIdx.x >> 6;
    int col = lane & 15, q = lane >> 4;
    const bf16x8* w1f = (const bf16x8*)w1s;

    f32x4 acc[4];
    #pragma unroll
    for (int u = 0; u < 4; ++u) acc[u] = (f32x4){0.f, 0.f, 0.f, 0.f};
    #pragma unroll
    for (int kt = 0; kt < 8; ++kt) {
        bf16x8 a = *(const bf16x8*)&hb[(size_t)(mm * 16 + col) * H_ + kt * 32 + q * 8];
        #pragma unroll
        for (int u = 0; u < 4; ++u) {
            bf16x8 w = w1f[(size_t)((ty * 16 + wid * 4 + u) * 16 + half * 8 + kt) * 64 + lane];
            acc[u] = __builtin_amdgcn_mfma_f32_16x16x32_bf16(a, w, acc[u], 0, 0, 0);
        }
    }
    #pragma unroll
    for (int u = 0; u < 4; ++u) {
        float bias = (half == 0) ? b1[(ty + 1) * H_ + (wid * 4 + u) * 16 + col] : 0.0f;
        #pragma unroll
        for (int r = 0; r < 4; ++r)
            UV[((size_t)(mm * 16 + q * 4 + r) * 3 + ty) * 512 + half * 256 +
               (wid * 4 + u) * 16 + col] = acc[u][r] + bias;
    }
}

__device__ __forceinline__ void msgagg_body(
        int ty, int b, int r, char* smem,
        const float* __restrict__ UV, const float* __restrict__ edges,
        const unsigned short* __restrict__ w2s, const float* __restrict__ b2,
        float* __restrict__ aggP, int t) {
    unsigned short* m1F = (unsigned short*)smem;          // 32 KB
    float* relS = (float*)(smem + 32768);                 // 256 B

    int tid = threadIdx.x;
    int lane = tid & 63, wid = tid >> 6;
    int col = lane & 15, q = lane >> 4;

    __syncthreads();   // protect LDS reuse across units/phases

    if (tid < 64) {
        float v = 0.0f;
        if (tid < 50 && tid != r) {
            int e = tid * 49 + (r > tid ? r - 1 : r);
            v = edges[(((size_t)b * T_ + t) * E_ + e) * K_ + ty + 1];
        }
        relS[tid] = v;
    }
    {
        int row = wid * 16 + col;
        int sv = row < N_ ? row : N_ - 1;
        float fl = (row < N_) ? 1.0f : 0.0f;
        const float* Vrow = &UV[((size_t)(b * N_ + sv) * 3 + ty) * 512 + 256 + q * 8];
        const float* Urow = &UV[((size_t)(b * N_ + r) * 3 + ty) * 512 + q * 8];
        #pragma unroll
        for (int kt = 0; kt < 8; ++kt) {
            float4 v0 = *(const float4*)(Vrow + kt * 32);
            float4 v1 = *(const float4*)(Vrow + kt * 32 + 4);
            float4 u0 = *(const float4*)(Urow + kt * 32);
            float4 u1 = *(const float4*)(Urow + kt * 32 + 4);
            float m0 = tanh_fast(u0.x + v0.x) * fl;
            float m1 = tanh_fast(u0.y + v0.y) * fl;
            float m2 = tanh_fast(u0.z + v0.z) * fl;
            float m3 = tanh_fast(u0.w + v0.w) * fl;
            float m4 = tanh_fast(u1.x + v1.x) * fl;
            float m5 = tanh_fast(u1.y + v1.y) * fl;
            float m6 = tanh_fast(u1.z + v1.z) * fl;
            float m7 = tanh_fast(u1.w + v1.w) * fl;
            uint4 pk;
            pk.x = pk2(m0, m1); pk.y = pk2(m2, m3);
            pk.z = pk2(m4, m5); pk.w = pk2(m6, m7);
            *(uint4*)&m1F[(wid * 8 + kt) * 512 + lane * 8] = pk;
        }
    }
    __syncthreads();

    const bf16x8* w2f = (const bf16x8*)w2s;
    f32x4 acc[4][4];
    #pragma unroll
    for (int mt = 0; mt < 4; ++mt)
        #pragma unroll
        for (int u = 0; u < 4; ++u) acc[mt][u] = (f32x4){0.f, 0.f, 0.f, 0.f};

    #pragma unroll
    for (int kt = 0; kt < 8; ++kt) {
        bf16x8 a0 = *(const bf16x8*)&m1F[(0 * 8 + kt) * 512 + lane * 8];
        bf16x8 a1 = *(const bf16x8*)&m1F[(1 * 8 + kt) * 512 + lane * 8];
        bf16x8 a2 = *(const bf16x8*)&m1F[(2 * 8 + kt) * 512 + lane * 8];
        bf16x8 a3 = *(const bf16x8*)&m1F[(3 * 8 + kt) * 512 + lane * 8];
        #pragma unroll
        for (int u = 0; u < 4; ++u) {
            bf16x8 w = w2f[(size_t)((ty * 16 + wid * 4 + u) * 8 + kt) * 64 + lane];
            acc[0][u] = __builtin_amdgcn_mfma_f32_16x16x32_bf16(a0, w, acc[0][u], 0, 0, 0);
            acc[1][u] = __builtin_amdgcn_mfma_f32_16x16x32_bf16(a1, w, acc[1][u], 0, 0, 0);
            acc[2][u] = __builtin_amdgcn_mfma_f32_16x16x32_bf16(a2, w, acc[2][u], 0, 0, 0);
            acc[3][u] = __builtin_amdgcn_mfma_f32_16x16x32_bf16(a3, w, acc[3][u], 0, 0, 0);
        }
    }
    #pragma unroll
    for (int u = 0; u < 4; ++u) {
        float bias = b2[(ty + 1) * H_ + (wid * 4 + u) * 16 + col];
        float sum = 0.0f;
        #pragma unroll
        for (int mt = 0; mt < 4; ++mt)
            #pragma unroll
            for (int rg = 0; rg < 4; ++rg) {
                int row = mt * 16 + q * 4 + rg;
                sum += tanh_fast(acc[mt][u][rg] + bias) * relS[row];
            }
        sum += __shfl_xor(sum, 16);
        sum += __shfl_xor(sum, 32);
        if (lane < 16)
            aggP[(size_t)ty * AP + (size_t)(b * N_ + r) * H_ +
                 (wid * 4 + u) * 16 + col] = sum * (1.0f / 147.0f);
    }
}

__device__ __forceinline__ void node_body(
        int mm, char* smem,
        const float* __restrict__ inputs, const float* __restrict__ aggP,
        const unsigned short* __restrict__ gws, const unsigned short* __restrict__ wos,
        float* __restrict__ hidden, unsigned short* __restrict__ hidden_bf,
        const float* __restrict__ w_ir, const float* __restrict__ b_ir,
        const float* __restrict__ w_ii, const float* __restrict__ b_ii,
        const float* __restrict__ w_in, const float* __restrict__ b_in,
        const float* __restrict__ b_o1, const float* __restrict__ b_o2,
        const float* __restrict__ w_o3, const float* __restrict__ b_o3,
        float* __restrict__ out, int t) {
    unsigned short* aggF = (unsigned short*)smem;          // 8 KB
    unsigned short* hnF  = (unsigned short*)(smem + 8192); // 8 KB
    unsigned short* p1F  = (unsigned short*)(smem + 16384);// 8 KB
    float* p2L = (float*)(smem + 24576);                   // 16.64 KB (16x260)
    float* insS = (float*)(smem + 41216);                  // 384 B

    int tid = threadIdx.x;
    int lane = tid & 63, wid = tid >> 6;
    int col = lane & 15, q = lane >> 4;

    const float* src = (t == 0) ? inputs : out;
    int tt = (t == 0) ? 0 : (t - 1);

    __syncthreads();   // protect LDS reuse across phases

    #pragma unroll
    for (int s = 0; s < 2; ++s) {
        int slot = tid + s * 256;
        int kt = slot >> 6, L = slot & 63;
        int row = mm * 16 + (L & 15);
        int k0 = kt * 32 + ((L >> 4) << 3);
        const float* p = &aggP[(size_t)row * H_ + k0];
        float4 a0 = *(const float4*)(p);
        float4 a1 = *(const float4*)(p + 4);
        float4 b0 = *(const float4*)(p + AP);
        float4 b1 = *(const float4*)(p + AP + 4);
        float4 c0 = *(const float4*)(p + 2 * AP);
        float4 c1 = *(const float4*)(p + 2 * AP + 4);
        uint4 pk;
        pk.x = pk2(a0.x + b0.x + c0.x, a0.y + b0.y + c0.y);
        pk.y = pk2(a0.z + b0.z + c0.z, a0.w + b0.w + c0.w);
        pk.z = pk2(a1.x + b1.x + c1.x, a1.y + b1.y + c1.y);
        pk.w = pk2(a1.z + b1.z + c1.z, a1.w + b1.w + c1.w);
        *(uint4*)&aggF[(size_t)kt * 512 + L * 8] = pk;
    }
    if (tid < 96) {
        int rl = tid / 6, c = tid - rl * 6;
        int row = mm * 16 + rl;
        int b = row / 50, n = row - b * 50;
        insS[rl * 6 + c] = src[(((size_t)b * T_ + tt) * N_ + n) * IN_ + c];
    }
    __syncthreads();

    const bf16x8* gwf = (const bf16x8*)gws;
    f32x4 acc[3][4];
    #pragma unroll
    for (int m = 0; m < 3; ++m)
        #pragma unroll
        for (int u = 0; u < 4; ++u) acc[m][u] = (f32x4){0.f, 0.f, 0.f, 0.f};
    #pragma unroll
    for (int kt = 0; kt < 8; ++kt) {
        bf16x8 a = *(const bf16x8*)&aggF[kt * 512 + lane * 8];
        #pragma unroll
        for (int m = 0; m < 3; ++m)
            #pragma unroll
            for (int u = 0; u < 4; ++u) {
                bf16x8 w = gwf[(size_t)((m * 16 + wid * 4 + u) * 8 + kt) * 64 + lane];
                acc[m][u] = __builtin_amdgcn_mfma_f32_16x16x32_bf16(a, w, acc[m][u], 0, 0, 0);
            }
    }

    #pragma unroll
    for (int u = 0; u < 4; ++u) {
        int h = (wid * 4 + u) * 16 + col;
        float bir = b_ir[h], bii = b_ii[h], bin_ = b_in[h];
        float wir[6], wii[6], win[6];
        #pragma unroll
        for (int c = 0; c < 6; ++c) {
            wir[c] = w_ir[h * 6 + c];
            wii[c] = w_ii[h * 6 + c];
            win[c] = w_in[h * 6 + c];
        }
        #pragma unroll
        for (int rg = 0; rg < 4; ++rg) {
            int rl = q * 4 + rg;
            int row = mm * 16 + rl;
            float xr = bir, xi = bii, xn = bin_;
            #pragma unroll
            for (int c = 0; c < 6; ++c) {
                float iv = insS[rl * 6 + c];
                xr += wir[c] * iv;
                xi += wii[c] * iv;
                xn += win[c] * iv;
            }
            float rgate = sigmoid_fast(xr + acc[0][u][rg]);
            float igate = sigmoid_fast(xi + acc[1][u][rg]);
            float nn = tanh_fast(xn + rgate * acc[2][u][rg]);
            size_t off = (size_t)row * H_ + h;
            float hold = hidden[off];
            float hnew = (1.0f - igate) * nn + igate * hold;
            hidden[off] = hnew;
            hidden_bf[off] = f2bf(hnew);
            hnF[(h >> 5) * 512 + (((h >> 3) & 3) * 16 + rl) * 8 + (h & 7)] = f2bf(hnew);
        }
    }
    __syncthreads();

    const bf16x8* wof = (const bf16x8*)wos;
    f32x4 a1v[4];
    #pragma unroll
    for (int u = 0; u < 4; ++u) a1v[u] = (f32x4){0.f, 0.f, 0.f, 0.f};
    #pragma unroll
    for (int kt = 0; kt < 8; ++kt) {
        bf16x8 a = *(const bf16x8*)&hnF[kt * 512 + lane * 8];
        #pragma unroll
        for (int u = 0; u < 4; ++u) {
            bf16x8 w = wof[(size_t)((wid * 4 + u) * 8 + kt) * 64 + lane];
            a1v[u] = __builtin_amdgcn_mfma_f32_16x16x32_bf16(a, w, a1v[u], 0, 0, 0);
        }
    }
    #pragma unroll
    for (int u = 0; u < 4; ++u) {
        int h = (wid * 4 + u) * 16 + col;
        float bo = b_o1[h];
        #pragma unroll
        for (int rg = 0; rg < 4; ++rg) {
            int rl = q * 4 + rg;
            float v = fmaxf(a1v[u][rg] + bo, 0.0f);
            p1F[(h >> 5) * 512 + (((h >> 3) & 3) * 16 + rl) * 8 + (h & 7)] = f2bf(v);
        }
    }
    __syncthreads();

    f32x4 a2v[4];
    #pragma unroll
    for (int u = 0; u < 4; ++u) a2v[u] = (f32x4){0.f, 0.f, 0.f, 0.f};
    #pragma unroll
    for (int kt = 0; kt < 8; ++kt) {
        bf16x8 a = *(const bf16x8*)&p1F[kt * 512 + lane * 8];
        #pragma unroll
        for (int u = 0; u < 4; ++u) {
            bf16x8 w = wof[(size_t)((16 + wid * 4 + u) * 8 + kt) * 64 + lane];
            a2v[u] = __builtin_amdgcn_mfma_f32_16x16x32_bf16(a, w, a2v[u], 0, 0, 0);
        }
    }
    #pragma unroll
    for (int u = 0; u < 4; ++u) {
        int h = (wid * 4 + u) * 16 + col;
        float bo = b_o2[h];
        #pragma unroll
        for (int rg = 0; rg < 4; ++rg) {
            int rl = q * 4 + rg;
            p2L[rl * 260 + h] = fmaxf(a2v[u][rg] + bo, 0.0f);
        }
    }
    __syncthreads();

    if (tid < 96) {
        int rl = tid / 6, c = tid - rl * 6;
        int row = mm * 16 + rl;
        float acc3 = b_o3[c];
        for (int k = 0; k < 256; k += 4) {
            float4 w = *(const float4*)&w_o3[c * 256 + k];
            float4 p = *(const float4*)&p2L[rl * 260 + k];
            acc3 += w.x * p.x + w.y * p.y + w.z * p.z + w.w * p.w;
        }
        int b = row / 50, n = row - b * 50;
        out[(((size_t)b * T_ + t) * N_ + n) * IN_ + c] = insS[rl * 6 + c] + acc3;
    }
}

// ---------------- persistent step kernel (normal launch, 256 blocks) -------------
__global__ __launch_bounds__(256) void step_kernel(
        const float* __restrict__ inputs, const float* __restrict__ edges,
        const float* __restrict__ msg_b1, const float* __restrict__ msg_b2,
        const float* __restrict__ w_ir, const float* __restrict__ b_ir,
        const float* __restrict__ w_ii, const float* __restrict__ b_ii,
        const float* __restrict__ w_in, const float* __restrict__ b_in,
        const float* __restrict__ b_o1, const float* __restrict__ b_o2,
        const float* __restrict__ w_o3, const float* __restrict__ b_o3,
        float* __restrict__ out, char* __restrict__ ws) {
    __shared__ __align__(16) char smem[41600];

    float* hidden             = (float*)(ws);
    unsigned short* hidden_bf = (unsigned short*)(ws + 409600);
    unsigned* barcnt          = (unsigned*)(ws + 614400);
    float* UV                 = (float*)(ws + 614656);
    float* aggP               = (float*)(ws + 3072256);
    const unsigned short* w1s = (const unsigned short*)(ws + 4301056);
    const unsigned short* w2s = (const unsigned short*)(ws + 5087488);
    const unsigned short* gws = (const unsigned short*)(ws + 5480704);
    const unsigned short* wos = (const unsigned short*)(ws + 5873920);

    int bid = blockIdx.x;
    unsigned bar = 0;

    for (int t = 0; t < T_; ++t) {
        // phase A: uv (150 units on blocks 0-149)
        if (bid < 150) uv_body(bid, hidden_bf, w1s, msg_b1, UV);
        gridbar(barcnt, bar++);
        // phase B: msgagg (1200 units, strided over 256 blocks: 4-5 each)
        for (int unit = bid; unit < 1200; unit += NBLK) {
            int ty = unit / 400;
            int rem = unit - ty * 400;
            int b = rem / 50, r = rem - (rem / 50) * 50;
            msgagg_body(ty, b, r, smem, UV, edges, w2s, msg_b2, aggP, t);
        }
        gridbar(barcnt, bar++);
        // phase C: node (25 units on blocks 0-24)
        if (bid < 25)
            node_body(bid, smem, inputs, aggP, gws, wos, hidden, hidden_bf,
                      w_ir, b_ir, w_ii, b_ii, w_in, b_in, b_o1, b_o2, w_o3, b_o3,
                      out, t);
        gridbar(barcnt, bar++);
    }
}

extern "C" void kernel_launch(void* const* d_in, const int* in_sizes, int n_in,
                              void* d_out, int out_size, void* d_ws, size_t ws_size,
                              hipStream_t stream) {
    const float* inputs = (const float*)d_in[0];
    const float* edges  = (const float*)d_in[1];
    const float* msg_w1 = (const float*)d_in[2];
    const float* msg_b1 = (const float*)d_in[3];
    const float* msg_w2 = (const float*)d_in[4];
    const float* msg_b2 = (const float*)d_in[5];
    const float* w_hr = (const float*)d_in[6];
    const float* w_hi = (const float*)d_in[7];
    const float* w_hh = (const float*)d_in[8];
    const float* w_ir = (const float*)d_in[9];
    const float* b_ir = (const float*)d_in[10];
    const float* w_ii = (const float*)d_in[11];
    const float* b_ii = (const float*)d_in[12];
    const float* w_in = (const float*)d_in[13];
    const float* b_in = (const float*)d_in[14];
    const float* w_o1 = (const float*)d_in[15];
    const float* b_o1 = (const float*)d_in[16];
    const float* w_o2 = (const float*)d_in[17];
    const float* b_o2 = (const float*)d_in[18];
    const float* w_o3 = (const float*)d_in[19];
    const float* b_o3 = (const float*)d_in[20];
    float* out = (float*)d_out;
    char* wsp = (char*)d_ws;

    unsigned short* w1s = (unsigned short*)(wsp + 4301056);
    unsigned short* w2s = (unsigned short*)(wsp + 5087488);
    unsigned short* gws = (unsigned short*)(wsp + 5480704);
    unsigned short* wos = (unsigned short*)(wsp + 5873920);

    // setup: swizzle weights + zero hidden/hidden_bf/barrier (153664 words)
    swizzle_weights<<<dim3(4185), dim3(256), 0, stream>>>(
        msg_w1, msg_w2, w_hr, w_hi, w_hh, w_o1, w_o2, w1s, w2s, gws, wos,
        (unsigned int*)wsp);

    step_kernel<<<dim3(NBLK), dim3(256), 0, stream>>>(
        inputs, edges, msg_b1, msg_b2, w_ir, b_ir, w_ii, b_ii, w_in, b_in,
        b_o1, b_o2, w_o3, b_o3, out, wsp);
}

// Round 9
// 619.328 us; speedup vs baseline: 3.2854x; 3.2854x over previous
//
#include <hip/hip_runtime.h>
#include <hip/hip_bf16.h>
#include <stdint.h>

#define B_ 8
#define T_ 10
#define N_ 50
#define IN_ 6
#define H_ 256
#define K_ 4
#define E_ 2450
#define ROWS 400           // B_*N_
#define AP 102400          // ROWS*H_

typedef __attribute__((ext_vector_type(8))) __bf16 bf16x8;
typedef __attribute__((ext_vector_type(4))) float f32x4;

__device__ __forceinline__ unsigned short f2bf(float x) {
    unsigned int u = __float_as_uint(x);
    u = (u + 0x7fffu + ((u >> 16) & 1u)) >> 16;   // RNE
    return (unsigned short)u;
}
__device__ __forceinline__ unsigned pk2(float a, float b) {
    return (unsigned)f2bf(a) | ((unsigned)f2bf(b) << 16);
}
__device__ __forceinline__ float rcp_fast(float x) { return __builtin_amdgcn_rcpf(x); }
__device__ __forceinline__ float tanh_fast(float x) {
    float e = __expf(2.0f * x);
    return 1.0f - 2.0f * rcp_fast(e + 1.0f);
}
__device__ __forceinline__ float sigmoid_fast(float x) {
    return rcp_fast(1.0f + __expf(-x));
}

// ---------------- setup: weight swizzle + zero hidden buffer 0 -------------------
__global__ __launch_bounds__(256) void swizzle_weights(
        const float* __restrict__ w1, const float* __restrict__ w2,
        const float* __restrict__ whr, const float* __restrict__ whi,
        const float* __restrict__ whh, const float* __restrict__ wo1,
        const float* __restrict__ wo2,
        unsigned short* __restrict__ w1s, unsigned short* __restrict__ w2s,
        unsigned short* __restrict__ gws, unsigned short* __restrict__ wos,
        unsigned int* __restrict__ zero_region) {
    const int W1N = 3 * 16 * 16 * 64 * 8;   // 393216
    const int W2N = 3 * 16 * 8 * 64 * 8;    // 196608
    const int GWN = 3 * 65536;              // 196608
    const int WON = 2 * 65536;              // 131072
    int idx = blockIdx.x * 256 + threadIdx.x;
    if (idx < W1N) {
        int j = idx & 7, L = (idx >> 3) & 63, kt = (idx >> 9) & 15;
        int nt = (idx >> 13) & 15, i = idx >> 17;
        int n = nt * 16 + (L & 15);
        int k = kt * 32 + ((L >> 4) << 3) + j;
        w1s[idx] = f2bf(w1[((size_t)(i + 1) * H_ + n) * (2 * H_) + k]);
    } else if (idx < W1N + W2N) {
        int t = idx - W1N;
        int j = t & 7, L = (t >> 3) & 63, kt = (t >> 9) & 7;
        int nt = (t >> 12) & 15, i = t >> 16;
        int n = nt * 16 + (L & 15);
        int k = kt * 32 + ((L >> 4) << 3) + j;
        w2s[t] = f2bf(w2[((size_t)(i + 1) * H_ + n) * H_ + k]);
    } else if (idx < W1N + W2N + GWN) {
        int t = idx - (W1N + W2N);
        int j = t & 7, L = (t >> 3) & 63, kt = (t >> 9) & 7;
        int nt = (t >> 12) & 15, mat = t >> 16;
        int n = nt * 16 + (L & 15);
        int k = kt * 32 + ((L >> 4) << 3) + j;
        const float* src = (mat == 0) ? whr : (mat == 1) ? whi : whh;
        gws[t] = f2bf(src[(size_t)n * H_ + k]);
    } else if (idx < W1N + W2N + GWN + WON) {
        int t = idx - (W1N + W2N + GWN);
        int j = t & 7, L = (t >> 3) & 63, kt = (t >> 9) & 7;
        int nt = (t >> 12) & 15, g = t >> 16;
        int n = nt * 16 + (L & 15);
        int k = kt * 32 + ((L >> 4) << 3) + j;
        const float* src = (g == 0) ? wo1 : wo2;
        wos[t] = f2bf(src[(size_t)n * H_ + k]);
    } else {
        int t = idx - (W1N + W2N + GWN + WON);
        if (t < 102400) zero_region[t] = 0u;   // hidden buffer 0
    }
}

// ---------------- node body: gates + GRU + o1/o2/o3; leaves hn A-frags in hnF ----
__device__ __forceinline__ void node_part(
        int mm, int tstep, unsigned short* aggF, unsigned short* hnF,
        unsigned short* p1F, float* p2L, float* insS,
        const float* __restrict__ inputs, const float* __restrict__ aggP,
        const unsigned short* __restrict__ gws, const unsigned short* __restrict__ wos,
        const float* __restrict__ hidden_old, float* __restrict__ hidden_new,
        const float* __restrict__ w_ir, const float* __restrict__ b_ir,
        const float* __restrict__ w_ii, const float* __restrict__ b_ii,
        const float* __restrict__ w_in, const float* __restrict__ b_in,
        const float* __restrict__ b_o1, const float* __restrict__ b_o2,
        const float* __restrict__ w_o3, const float* __restrict__ b_o3,
        float* __restrict__ out) {
    int tid = threadIdx.x;
    int lane = tid & 63, wid = tid >> 6;
    int col = lane & 15, q = lane >> 4;

    const float* src = (tstep == 0) ? inputs : out;
    int tt = (tstep == 0) ? 0 : (tstep - 1);

    #pragma unroll
    for (int s = 0; s < 2; ++s) {
        int slot = tid + s * 256;
        int kt = slot >> 6, L = slot & 63;
        int row = mm * 16 + (L & 15);
        int k0 = kt * 32 + ((L >> 4) << 3);
        const float* p = &aggP[(size_t)row * H_ + k0];
        float4 a0 = *(const float4*)(p);
        float4 a1 = *(const float4*)(p + 4);
        float4 b0 = *(const float4*)(p + AP);
        float4 b1 = *(const float4*)(p + AP + 4);
        float4 c0 = *(const float4*)(p + 2 * AP);
        float4 c1 = *(const float4*)(p + 2 * AP + 4);
        uint4 pk;
        pk.x = pk2(a0.x + b0.x + c0.x, a0.y + b0.y + c0.y);
        pk.y = pk2(a0.z + b0.z + c0.z, a0.w + b0.w + c0.w);
        pk.z = pk2(a1.x + b1.x + c1.x, a1.y + b1.y + c1.y);
        pk.w = pk2(a1.z + b1.z + c1.z, a1.w + b1.w + c1.w);
        *(uint4*)&aggF[(size_t)kt * 512 + L * 8] = pk;
    }
    if (tid < 96) {
        int rl = tid / 6, c = tid - rl * 6;
        int row = mm * 16 + rl;
        int b = row / 50, n = row - b * 50;
        insS[rl * 6 + c] = src[(((size_t)b * T_ + tt) * N_ + n) * IN_ + c];
    }
    __syncthreads();

    const bf16x8* gwf = (const bf16x8*)gws;
    f32x4 acc[3][4];
    #pragma unroll
    for (int m = 0; m < 3; ++m)
        #pragma unroll
        for (int u = 0; u < 4; ++u) acc[m][u] = (f32x4){0.f, 0.f, 0.f, 0.f};
    #pragma unroll
    for (int kt = 0; kt < 8; ++kt) {
        bf16x8 a = *(const bf16x8*)&aggF[kt * 512 + lane * 8];
        #pragma unroll
        for (int m = 0; m < 3; ++m)
            #pragma unroll
            for (int u = 0; u < 4; ++u) {
                bf16x8 w = gwf[(size_t)((m * 16 + wid * 4 + u) * 8 + kt) * 64 + lane];
                acc[m][u] = __builtin_amdgcn_mfma_f32_16x16x32_bf16(a, w, acc[m][u], 0, 0, 0);
            }
    }

    #pragma unroll
    for (int u = 0; u < 4; ++u) {
        int h = (wid * 4 + u) * 16 + col;
        float bir = b_ir[h], bii = b_ii[h], bin_ = b_in[h];
        float wir[6], wii[6], win[6];
        #pragma unroll
        for (int c = 0; c < 6; ++c) {
            wir[c] = w_ir[h * 6 + c];
            wii[c] = w_ii[h * 6 + c];
            win[c] = w_in[h * 6 + c];
        }
        #pragma unroll
        for (int rg = 0; rg < 4; ++rg) {
            int rl = q * 4 + rg;
            int row = mm * 16 + rl;
            float xr = bir, xi = bii, xn = bin_;
            #pragma unroll
            for (int c = 0; c < 6; ++c) {
                float iv = insS[rl * 6 + c];
                xr += wir[c] * iv;
                xi += wii[c] * iv;
                xn += win[c] * iv;
            }
            float rgate = sigmoid_fast(xr + acc[0][u][rg]);
            float igate = sigmoid_fast(xi + acc[1][u][rg]);
            float nn = tanh_fast(xn + rgate * acc[2][u][rg]);
            size_t off = (size_t)row * H_ + h;
            float hold = hidden_old[off];
            float hnew = (1.0f - igate) * nn + igate * hold;
            hidden_new[off] = hnew;
            hnF[(h >> 5) * 512 + (((h >> 3) & 3) * 16 + rl) * 8 + (h & 7)] = f2bf(hnew);
        }
    }
    __syncthreads();

    const bf16x8* wof = (const bf16x8*)wos;
    f32x4 a1v[4];
    #pragma unroll
    for (int u = 0; u < 4; ++u) a1v[u] = (f32x4){0.f, 0.f, 0.f, 0.f};
    #pragma unroll
    for (int kt = 0; kt < 8; ++kt) {
        bf16x8 a = *(const bf16x8*)&hnF[kt * 512 + lane * 8];
        #pragma unroll
        for (int u = 0; u < 4; ++u) {
            bf16x8 w = wof[(size_t)((wid * 4 + u) * 8 + kt) * 64 + lane];
            a1v[u] = __builtin_amdgcn_mfma_f32_16x16x32_bf16(a, w, a1v[u], 0, 0, 0);
        }
    }
    #pragma unroll
    for (int u = 0; u < 4; ++u) {
        int h = (wid * 4 + u) * 16 + col;
        float bo = b_o1[h];
        #pragma unroll
        for (int rg = 0; rg < 4; ++rg) {
            int rl = q * 4 + rg;
            float v = fmaxf(a1v[u][rg] + bo, 0.0f);
            p1F[(h >> 5) * 512 + (((h >> 3) & 3) * 16 + rl) * 8 + (h & 7)] = f2bf(v);
        }
    }
    __syncthreads();

    f32x4 a2v[4];
    #pragma unroll
    for (int u = 0; u < 4; ++u) a2v[u] = (f32x4){0.f, 0.f, 0.f, 0.f};
    #pragma unroll
    for (int kt = 0; kt < 8; ++kt) {
        bf16x8 a = *(const bf16x8*)&p1F[kt * 512 + lane * 8];
        #pragma unroll
        for (int u = 0; u < 4; ++u) {
            bf16x8 w = wof[(size_t)((16 + wid * 4 + u) * 8 + kt) * 64 + lane];
            a2v[u] = __builtin_amdgcn_mfma_f32_16x16x32_bf16(a, w, a2v[u], 0, 0, 0);
        }
    }
    #pragma unroll
    for (int u = 0; u < 4; ++u) {
        int h = (wid * 4 + u) * 16 + col;
        float bo = b_o2[h];
        #pragma unroll
        for (int rg = 0; rg < 4; ++rg) {
            int rl = q * 4 + rg;
            p2L[rl * 260 + h] = fmaxf(a2v[u][rg] + bo, 0.0f);
        }
    }
    __syncthreads();

    if (tid < 96) {
        int rl = tid / 6, c = tid - rl * 6;
        int row = mm * 16 + rl;
        float acc3 = b_o3[c];
        for (int k = 0; k < 256; k += 4) {
            float4 w = *(const float4*)&w_o3[c * 256 + k];
            float4 p = *(const float4*)&p2L[rl * 260 + k];
            acc3 += w.x * p.x + w.y * p.y + w.z * p.z + w.w * p.w;
        }
        int b = row / 50, n = row - b * 50;
        out[(((size_t)b * T_ + tstep) * N_ + n) * IN_ + c] = insS[rl * 6 + c] + acc3;
    }
}

// ---------------- fused node(t-1) + uv(t). Grid 150 = mm(25) x tyh(6). -----------
__global__ __launch_bounds__(256) void nodeuv_kernel(
        const float* __restrict__ inputs, const float* __restrict__ aggP,
        const unsigned short* __restrict__ gws, const unsigned short* __restrict__ wos,
        const unsigned short* __restrict__ w1s, const float* __restrict__ msg_b1,
        float* __restrict__ hbuf0, float* __restrict__ hbuf1,
        const float* __restrict__ w_ir, const float* __restrict__ b_ir,
        const float* __restrict__ w_ii, const float* __restrict__ b_ii,
        const float* __restrict__ w_in, const float* __restrict__ b_in,
        const float* __restrict__ b_o1, const float* __restrict__ b_o2,
        const float* __restrict__ w_o3, const float* __restrict__ b_o3,
        float* __restrict__ out, float* __restrict__ UV, int t) {
    __shared__ unsigned short aggF[8 * 512];
    __shared__ unsigned short hnF[8 * 512];
    __shared__ unsigned short p1F[8 * 512];
    __shared__ float p2L[16 * 260];
    __shared__ float insS[16 * 6];

    int mm = blockIdx.x / 6;
    int tyh = blockIdx.x % 6;
    int ty = tyh >> 1, half = tyh & 1;
    int tid = threadIdx.x;
    int lane = tid & 63, wid = tid >> 6;
    int col = lane & 15, q = lane >> 4;

    if (t > 0) {
        const float* hold = ((t - 1) & 1) ? hbuf1 : hbuf0;
        float* hnew = (t & 1) ? hbuf1 : hbuf0;
        node_part(mm, t - 1, aggF, hnF, p1F, p2L, insS,
                  inputs, aggP, gws, wos, hold, hnew,
                  w_ir, b_ir, w_ii, b_ii, w_in, b_in, b_o1, b_o2, w_o3, b_o3, out);
    } else {
        // h0 = 0: zero hnF
        #pragma unroll
        for (int s = 0; s < 2; ++s)
            *(uint4*)&hnF[(tid + s * 256) * 8] = make_uint4(0u, 0u, 0u, 0u);
    }
    __syncthreads();

    // uv part: A-frags straight from hnF
    const bf16x8* w1f = (const bf16x8*)w1s;
    f32x4 acc[4];
    #pragma unroll
    for (int u = 0; u < 4; ++u) acc[u] = (f32x4){0.f, 0.f, 0.f, 0.f};
    #pragma unroll
    for (int kt = 0; kt < 8; ++kt) {
        bf16x8 a = *(const bf16x8*)&hnF[kt * 512 + lane * 8];
        #pragma unroll
        for (int u = 0; u < 4; ++u) {
            bf16x8 w = w1f[(size_t)((ty * 16 + wid * 4 + u) * 16 + half * 8 + kt) * 64 + lane];
            acc[u] = __builtin_amdgcn_mfma_f32_16x16x32_bf16(a, w, acc[u], 0, 0, 0);
        }
    }
    #pragma unroll
    for (int u = 0; u < 4; ++u) {
        float bias = (half == 0) ? msg_b1[(ty + 1) * H_ + (wid * 4 + u) * 16 + col] : 0.0f;
        #pragma unroll
        for (int r = 0; r < 4; ++r)
            UV[((size_t)(mm * 16 + q * 4 + r) * 3 + ty) * 512 + half * 256 +
               (wid * 4 + u) * 16 + col] = acc[u][r] + bias;
    }
}

// ---------------- final node (t = T-1). Grid 25. ---------------------------------
__global__ __launch_bounds__(256) void node_final_kernel(
        const float* __restrict__ inputs, const float* __restrict__ aggP,
        const unsigned short* __restrict__ gws, const unsigned short* __restrict__ wos,
        float* __restrict__ hbuf0, float* __restrict__ hbuf1,
        const float* __restrict__ w_ir, const float* __restrict__ b_ir,
        const float* __restrict__ w_ii, const float* __restrict__ b_ii,
        const float* __restrict__ w_in, const float* __restrict__ b_in,
        const float* __restrict__ b_o1, const float* __restrict__ b_o2,
        const float* __restrict__ w_o3, const float* __restrict__ b_o3,
        float* __restrict__ out) {
    __shared__ unsigned short aggF[8 * 512];
    __shared__ unsigned short hnF[8 * 512];
    __shared__ unsigned short p1F[8 * 512];
    __shared__ float p2L[16 * 260];
    __shared__ float insS[16 * 6];
    const int t = T_ - 1;
    const float* hold = ((t) & 1) ? hbuf1 : hbuf0;   // t=9 odd -> hbuf1
    float* hnew = ((t + 1) & 1) ? hbuf1 : hbuf0;     // write hbuf0
    node_part(blockIdx.x, t, aggF, hnF, p1F, p2L, insS,
              inputs, aggP, gws, wos, hold, hnew,
              w_ir, b_ir, w_ii, b_ii, w_in, b_in, b_o1, b_o2, w_o3, b_o3, out);
}

// ---------------- msgagg: m1-build + GEMM2 + sender reduction (1200 blocks) ------
__global__ __launch_bounds__(256, 4) void msgagg_kernel(
        const float* __restrict__ UV, const float* __restrict__ edges,
        const unsigned short* __restrict__ w2s,
        const float* __restrict__ b2, float* __restrict__ aggP, int t) {
    __shared__ unsigned short m1F[32 * 512];
    __shared__ float relS[64];

    int ty = blockIdx.x / 400;
    int rem = blockIdx.x - ty * 400;
    int b = rem / 50;
    int r = rem - b * 50;
    int tid = threadIdx.x;
    int lane = tid & 63, wid = tid >> 6;
    int col = lane & 15, q = lane >> 4;

    if (tid < 64) {
        float v = 0.0f;
        if (tid < 50 && tid != r) {
            int e = tid * 49 + (r > tid ? r - 1 : r);
            v = edges[(((size_t)b * T_ + t) * E_ + e) * K_ + ty + 1];
        }
        relS[tid] = v;
    }
    {
        int row = wid * 16 + col;
        int sv = row < N_ ? row : N_ - 1;
        float fl = (row < N_) ? 1.0f : 0.0f;
        const float* Vrow = &UV[((size_t)(b * N_ + sv) * 3 + ty) * 512 + 256 + q * 8];
        const float* Urow = &UV[((size_t)(b * N_ + r) * 3 + ty) * 512 + q * 8];
        #pragma unroll
        for (int kt = 0; kt < 8; ++kt) {
            float4 v0 = *(const float4*)(Vrow + kt * 32);
            float4 v1 = *(const float4*)(Vrow + kt * 32 + 4);
            float4 u0 = *(const float4*)(Urow + kt * 32);
            float4 u1 = *(const float4*)(Urow + kt * 32 + 4);
            float m0 = tanh_fast(u0.x + v0.x) * fl;
            float m1 = tanh_fast(u0.y + v0.y) * fl;
            float m2 = tanh_fast(u0.z + v0.z) * fl;
            float m3 = tanh_fast(u0.w + v0.w) * fl;
            float m4 = tanh_fast(u1.x + v1.x) * fl;
            float m5 = tanh_fast(u1.y + v1.y) * fl;
            float m6 = tanh_fast(u1.z + v1.z) * fl;
            float m7 = tanh_fast(u1.w + v1.w) * fl;
            uint4 pk;
            pk.x = pk2(m0, m1); pk.y = pk2(m2, m3);
            pk.z = pk2(m4, m5); pk.w = pk2(m6, m7);
            *(uint4*)&m1F[(wid * 8 + kt) * 512 + lane * 8] = pk;
        }
    }
    __syncthreads();

    const bf16x8* w2f = (const bf16x8*)w2s;
    f32x4 acc[4][4];
    #pragma unroll
    for (int mt = 0; mt < 4; ++mt)
        #pragma unroll
        for (int u = 0; u < 4; ++u) acc[mt][u] = (f32x4){0.f, 0.f, 0.f, 0.f};

    #pragma unroll
    for (int kt = 0; kt < 8; ++kt) {
        bf16x8 a0 = *(const bf16x8*)&m1F[(0 * 8 + kt) * 512 + lane * 8];
        bf16x8 a1 = *(const bf16x8*)&m1F[(1 * 8 + kt) * 512 + lane * 8];
        bf16x8 a2 = *(const bf16x8*)&m1F[(2 * 8 + kt) * 512 + lane * 8];
        bf16x8 a3 = *(const bf16x8*)&m1F[(3 * 8 + kt) * 512 + lane * 8];
        #pragma unroll
        for (int u = 0; u < 4; ++u) {
            bf16x8 w = w2f[(size_t)((ty * 16 + wid * 4 + u) * 8 + kt) * 64 + lane];
            acc[0][u] = __builtin_amdgcn_mfma_f32_16x16x32_bf16(a0, w, acc[0][u], 0, 0, 0);
            acc[1][u] = __builtin_amdgcn_mfma_f32_16x16x32_bf16(a1, w, acc[1][u], 0, 0, 0);
            acc[2][u] = __builtin_amdgcn_mfma_f32_16x16x32_bf16(a2, w, acc[2][u], 0, 0, 0);
            acc[3][u] = __builtin_amdgcn_mfma_f32_16x16x32_bf16(a3, w, acc[3][u], 0, 0, 0);
        }
    }
    #pragma unroll
    for (int u = 0; u < 4; ++u) {
        float bias = b2[(ty + 1) * H_ + (wid * 4 + u) * 16 + col];
        float sum = 0.0f;
        #pragma unroll
        for (int mt = 0; mt < 4; ++mt)
            #pragma unroll
            for (int rg = 0; rg < 4; ++rg) {
                int row = mt * 16 + q * 4 + rg;
                sum += tanh_fast(acc[mt][u][rg] + bias) * relS[row];
            }
        sum += __shfl_xor(sum, 16);
        sum += __shfl_xor(sum, 32);
        if (lane < 16)
            aggP[(size_t)ty * AP + (size_t)(b * N_ + r) * H_ +
                 (wid * 4 + u) * 16 + col] = sum * (1.0f / 147.0f);
    }
}

extern "C" void kernel_launch(void* const* d_in, const int* in_sizes, int n_in,
                              void* d_out, int out_size, void* d_ws, size_t ws_size,
                              hipStream_t stream) {
    const float* inputs = (const float*)d_in[0];
    const float* edges  = (const float*)d_in[1];
    const float* msg_w1 = (const float*)d_in[2];
    const float* msg_b1 = (const float*)d_in[3];
    const float* msg_w2 = (const float*)d_in[4];
    const float* msg_b2 = (const float*)d_in[5];
    const float* w_hr = (const float*)d_in[6];
    const float* w_hi = (const float*)d_in[7];
    const float* w_hh = (const float*)d_in[8];
    const float* w_ir = (const float*)d_in[9];
    const float* b_ir = (const float*)d_in[10];
    const float* w_ii = (const float*)d_in[11];
    const float* b_ii = (const float*)d_in[12];
    const float* w_in = (const float*)d_in[13];
    const float* b_in = (const float*)d_in[14];
    const float* w_o1 = (const float*)d_in[15];
    const float* b_o1 = (const float*)d_in[16];
    const float* w_o2 = (const float*)d_in[17];
    const float* b_o2 = (const float*)d_in[18];
    const float* w_o3 = (const float*)d_in[19];
    const float* b_o3 = (const float*)d_in[20];
    float* out = (float*)d_out;
    char* ws = (char*)d_ws;

    float* hbuf0         = (float*)(ws);                      // 409,600 B (zeroed)
    float* hbuf1         = (float*)(ws + 409600);             // 409,600 B
    float* UV            = (float*)(ws + 819200);             // 2,457,600 B
    float* aggP          = (float*)(ws + 3276800);            // 1,228,800 B
    unsigned short* w1s  = (unsigned short*)(ws + 4505600);   // 786,432 B
    unsigned short* w2s  = (unsigned short*)(ws + 5292032);   // 393,216 B
    unsigned short* gws  = (unsigned short*)(ws + 5685248);   // 393,216 B
    unsigned short* wos  = (unsigned short*)(ws + 6078464);   // 262,144 B

    // setup: swizzle all weights + zero hbuf0 (917504 + 102400 = 1019904 items)
    swizzle_weights<<<dim3(3984), dim3(256), 0, stream>>>(
        msg_w1, msg_w2, w_hr, w_hi, w_hh, w_o1, w_o2, w1s, w2s, gws, wos,
        (unsigned int*)ws);

    for (int t = 0; t < T_; ++t) {
        nodeuv_kernel<<<dim3(150), dim3(256), 0, stream>>>(
            inputs, aggP, gws, wos, w1s, msg_b1, hbuf0, hbuf1,
            w_ir, b_ir, w_ii, b_ii, w_in, b_in, b_o1, b_o2, w_o3, b_o3,
            out, UV, t);
        msgagg_kernel<<<dim3(1200), dim3(256), 0, stream>>>(
            UV, edges, w2s, msg_b2, aggP, t);
    }
    node_final_kernel<<<dim3(25), dim3(256), 0, stream>>>(
        inputs, aggP, gws, wos, hbuf0, hbuf1,
        w_ir, b_ir, w_ii, b_ii, w_in, b_in, b_o1, b_o2, w_o3, b_o3, out);
}